// Round 4
// baseline (68.428 us; speedup 1.0000x reference)
//
#include <hip/hip_runtime.h>
#include <math.h>

// ---------------------------------------------------------------------------
// RegressionLoss: chamfer(32x32 shape pairs of 256 3D pts) -> softmax vs
// normalized-embedding inner-product softmax -> mean |p_hat - p|.
// Inputs: d_in[0] = embeddings (64x512 f32), d_in[1] = xyz (64x256x3 f32).
// Output: d_out[0] single f32.
//
// R4: no-LDS chamfer. R3 was LDS-pipe-bound (~15.4 us: 16 waves/CU x 192
// broadcast ds_read_b128 x 12cyc). Inner-shape points are wave-UNIFORM ->
// read them straight from global with uniform addresses so the compiler
// scalarizes to s_load_dwordx16 (SMEM pipe, ~free), leaving 7 scalar VALU
// per point-pair (v_sub sgpr,vgpr x3; mul/fma x3; v_min). Predicted pairs
// phase ~6.5 us VALU-bound. Grid stays 992+32 = 1024 = exactly 4 blocks/CU.
// ---------------------------------------------------------------------------

__device__ __forceinline__ float waveReduceSum64(float v) {
    #pragma unroll
    for (int m = 32; m > 0; m >>= 1) v += __shfl_xor(v, m, 64);
    return v;
}

// blocks [0,992): directional chamfer half. pb=b>>1 indexes strict upper
//   triangle (i<j) of 32; dir=b&1. Writes cdHalf[b] = mean_p min_q d2.
// blocks [992,1024): dot row i=b-992 -> dots[i*32+j], j=0..31.
__global__ __launch_bounds__(256) void pairs_kernel(const float* __restrict__ emb,
                                                    const float* __restrict__ xyz,
                                                    float* __restrict__ cdHalf,
                                                    float* __restrict__ dots) {
    const int t = threadIdx.x;
    const int b = blockIdx.x;

    __shared__ float S[512];    // used by dots path only
    __shared__ float red[4];

    if (b < 992) {
        const int pb  = b >> 1;
        const int dir = b & 1;
        // strict-upper-triangle decode: row i has (31-i) entries
        int i = 0, rem = pb;
        while (rem >= (31 - i)) { rem -= (31 - i); ++i; }
        const int j = i + 1 + rem;

        const int outer = dir ? j : i;
        const int inner = dir ? i : j;

        const float* Po = xyz + (32 + outer) * 768;   // shapes = xyz[32:]
        const float* Pq = xyz + (32 + inner) * 768;   // uniform-address reads

        // my outer point (divergent, coalesced)
        const float px = Po[3*t], py = Po[3*t+1], pz = Po[3*t+2];

        float m0 = 3.4e38f, m1 = 3.4e38f;   // two accumulators: break dep chain
        #pragma unroll 8
        for (int s = 0; s < 256; s += 2) {
            // uniform addresses -> scalar loads (s_load_dwordx16 after merge)
            const float bx0 = Pq[3*s+0], by0 = Pq[3*s+1], bz0 = Pq[3*s+2];
            const float bx1 = Pq[3*s+3], by1 = Pq[3*s+4], bz1 = Pq[3*s+5];
            const float dx0 = px - bx0, dy0 = py - by0, dz0 = pz - bz0;
            const float dx1 = px - bx1, dy1 = py - by1, dz1 = pz - bz1;
            m0 = fminf(m0, dx0*dx0 + dy0*dy0 + dz0*dz0);
            m1 = fminf(m1, dx1*dx1 + dy1*dy1 + dz1*dz1);
        }
        const float mn = fminf(m0, m1);

        float v = waveReduceSum64(mn);
        if ((t & 63) == 0) red[t >> 6] = v;
        __syncthreads();
        if (t == 0)
            cdHalf[b] = (red[0] + red[1] + red[2] + red[3]) * (1.0f / 256.0f);
    } else {
        const int i = b - 992;    // sketch row 0..31
        float* rowi = S;          // 512 floats
        const float* Ei = emb + i * 512;
        rowi[t]       = Ei[t];
        rowi[t + 256] = Ei[t + 256];
        __syncthreads();

        const int w    = t >> 6;
        const int lane = t & 63;

        // norm^2 of sketch row i (redundant per wave, cheap)
        float ni = 0.0f;
        #pragma unroll
        for (int m = 0; m < 8; ++m) { float a = rowi[lane + 64*m]; ni += a*a; }
        ni = waveReduceSum64(ni);

        // 4 waves x 8 shape columns each
        for (int j = w; j < 32; j += 4) {
            const float* Ej = emb + (32 + j) * 512;
            float dot = 0.0f, nj = 0.0f;
            #pragma unroll
            for (int m = 0; m < 8; ++m) {
                float a  = rowi[lane + 64*m];
                float bv = Ej[lane + 64*m];
                dot += a * bv;
                nj  += bv * bv;
            }
            dot = waveReduceSum64(dot);
            nj  = waveReduceSum64(nj);
            if (lane == 0) dots[i * 32 + j] = dot * rsqrtf(ni * nj);
        }
    }
}

// 1 block x 1024 threads: assemble cd, softmaxes, mean abs diff
__global__ __launch_bounds__(1024) void finish_kernel(const float* __restrict__ cdHalf,
                                                      const float* __restrict__ dots,
                                                      float* __restrict__ out) {
    const int t = threadIdx.x;   // t = i*32 + j ; width-32 segments == rows
    const int i = t >> 5;
    const int j = t & 31;
    const float inv_denom = 1.0f / (2.0f * (0.997f / 3.0f) * (0.997f / 3.0f));

    float c;
    if (i == j) {
        c = 0.0f;                 // chamfer(self) == 0 (min includes q=p)
    } else {
        const int a  = min(i, j), bb = max(i, j);
        const int pb = a * 31 - (a * (a - 1)) / 2 + (bb - a - 1);
        c = cdHalf[2 * pb] + cdHalf[2 * pb + 1];
    }
    float s = -(c * c) * inv_denom;
    float h = dots[t];

    float m1 = s;
    #pragma unroll
    for (int k = 16; k > 0; k >>= 1) m1 = fmaxf(m1, __shfl_xor(m1, k, 32));
    float e1 = expf(s - m1);
    float sum1 = e1;
    #pragma unroll
    for (int k = 16; k > 0; k >>= 1) sum1 += __shfl_xor(sum1, k, 32);
    float p = e1 / sum1;

    float m2 = h;
    #pragma unroll
    for (int k = 16; k > 0; k >>= 1) m2 = fmaxf(m2, __shfl_xor(m2, k, 32));
    float e2 = expf(h - m2);
    float sum2 = e2;
    #pragma unroll
    for (int k = 16; k > 0; k >>= 1) sum2 += __shfl_xor(sum2, k, 32);
    float ph = e2 / sum2;

    float a = fabsf(ph - p);
    a = waveReduceSum64(a);

    __shared__ float red[16];
    if ((t & 63) == 0) red[t >> 6] = a;
    __syncthreads();
    if (t == 0) {
        float tot = 0.0f;
        #pragma unroll
        for (int k = 0; k < 16; ++k) tot += red[k];
        out[0] = tot * (1.0f / 1024.0f);
    }
}

extern "C" void kernel_launch(void* const* d_in, const int* in_sizes, int n_in,
                              void* d_out, int out_size, void* d_ws, size_t ws_size,
                              hipStream_t stream) {
    const float* emb = (const float*)d_in[0];   // 64 x 512
    const float* xyz = (const float*)d_in[1];   // 64 x 256 x 3
    float* cdHalf = (float*)d_ws;               // 992 directional halves
    float* dots   = cdHalf + 1024;              // 32x32
    float* out    = (float*)d_out;

    hipLaunchKernelGGL(pairs_kernel, dim3(1024), dim3(256), 0, stream, emb, xyz, cdHalf, dots);
    hipLaunchKernelGGL(finish_kernel, dim3(1), dim3(1024), 0, stream, cdHalf, dots, out);
}